// Round 5
// baseline (236.598 us; speedup 1.0000x reference)
//
#include <hip/hip_runtime.h>

#define Bdim 16
#define Ndim 8192
#define Fdim 256
#define EPS 1e-3f

#define RED_BLOCKS 512
#define NORM_BLOCKS 2048
#define TOTAL_CHUNKS (Bdim * Ndim * (Fdim / 4))        // 8388608 float4 chunks
#define NORM_ITERS (TOTAL_CHUNKS / (NORM_BLOCKS * 256)) // 16

typedef float fx4 __attribute__((ext_vector_type(4)));

// ws layout (floats): [0..255]=sum  [256..511]=sumsq

__global__ __launch_bounds__(512) void init_kernel(float* __restrict__ ws) {
    ws[threadIdx.x] = 0.0f;   // ws re-poisoned to 0xAA before every timed call
}

// Balanced reduce: valid rows (a prefix per batch) are enumerated 0..V-1 via
// prefix sums of nv[]; each block owns an equal contiguous strip of that valid
// index space. Mapping k->(batch,row) uses a register-cached boundary walk
// (LDS read only when crossing a batch boundary). Zero wasted loads, zero
// imbalance, no per-row branches on the fast path.
__global__ __launch_bounds__(256) void reduce_kernel(
    const float* __restrict__ x, const int* __restrict__ nv,
    float* __restrict__ ws)
{
    __shared__ float lds_s[4][Fdim];
    __shared__ float lds_q[4][Fdim];
    __shared__ int s_pre[Bdim + 1];     // prefix sums of nv
    const int tid = threadIdx.x;
    if (tid == 0) {
        int acc = 0;
        s_pre[0] = 0;
        #pragma unroll
        for (int i = 0; i < Bdim; i++) { acc += nv[i]; s_pre[i + 1] = acc; }
    }
    __syncthreads();

    const int V = s_pre[Bdim];
    // block g owns valid indices [k0, kE)
    const int per = V / RED_BLOCKS, rem = V % RED_BLOCKS;
    const int g = blockIdx.x;
    const int k0 = g * per + (g < rem ? g : rem);
    const int kE = k0 + per + (g < rem ? 1 : 0);

    const int c = tid & 63;      // float4 chunk within row (wave spans one row)
    const int r = tid >> 6;      // wave id 0..3
    const fx4* xc = (const fx4*)x + c;

    float s0=0.f,s1=0.f,s2=0.f,s3=0.f, q0=0.f,q1=0.f,q2=0.f,q3=0.f;

    int k = k0 + r;              // this wave's valid indices: k, k+4, k+8, ...
    int b = 0, pre_b = 0, pre_next = s_pre[1];
    if (k < kE) {
        while (k >= pre_next) { ++b; pre_b = pre_next; pre_next = s_pre[b + 1]; }
    }

    #define ROW_OF(kk, rowvar)                                                  \
        while ((kk) >= pre_next) { ++b; pre_b = pre_next; pre_next = s_pre[b+1]; } \
        const int rowvar = (b << 13) + ((kk) - pre_b);

    for (; k + 12 < kE; k += 16) {   // 4 independent 1KiB wave-loads in flight
        ROW_OF(k,      row0)
        ROW_OF(k + 4,  row1)
        ROW_OF(k + 8,  row2)
        ROW_OF(k + 12, row3)
        const fx4 v0 = xc[(size_t)row0 * 64];
        const fx4 v1 = xc[(size_t)row1 * 64];
        const fx4 v2 = xc[(size_t)row2 * 64];
        const fx4 v3 = xc[(size_t)row3 * 64];
        s0 += v0.x; q0 += v0.x*v0.x;  s1 += v0.y; q1 += v0.y*v0.y;
        s2 += v0.z; q2 += v0.z*v0.z;  s3 += v0.w; q3 += v0.w*v0.w;
        s0 += v1.x; q0 += v1.x*v1.x;  s1 += v1.y; q1 += v1.y*v1.y;
        s2 += v1.z; q2 += v1.z*v1.z;  s3 += v1.w; q3 += v1.w*v1.w;
        s0 += v2.x; q0 += v2.x*v2.x;  s1 += v2.y; q1 += v2.y*v2.y;
        s2 += v2.z; q2 += v2.z*v2.z;  s3 += v2.w; q3 += v2.w*v2.w;
        s0 += v3.x; q0 += v3.x*v3.x;  s1 += v3.y; q1 += v3.y*v3.y;
        s2 += v3.z; q2 += v3.z*v3.z;  s3 += v3.w; q3 += v3.w*v3.w;
    }
    for (; k < kE; k += 4) {
        ROW_OF(k, row)
        const fx4 v = xc[(size_t)row * 64];
        s0 += v.x; q0 += v.x*v.x;  s1 += v.y; q1 += v.y*v.y;
        s2 += v.z; q2 += v.z*v.z;  s3 += v.w; q3 += v.w*v.w;
    }
    #undef ROW_OF

    const int f0 = c * 4;
    lds_s[r][f0+0]=s0; lds_s[r][f0+1]=s1; lds_s[r][f0+2]=s2; lds_s[r][f0+3]=s3;
    lds_q[r][f0+0]=q0; lds_q[r][f0+1]=q1; lds_q[r][f0+2]=q2; lds_q[r][f0+3]=q3;
    __syncthreads();

    float ts = 0.0f, tq = 0.0f;
    #pragma unroll
    for (int rr = 0; rr < 4; rr++) { ts += lds_s[rr][tid]; tq += lds_q[rr][tid]; }
    unsafeAtomicAdd(&ws[tid], ts);          // hw global_atomic_add_f32
    unsafeAtomicAdd(&ws[Fdim + tid], tq);
}

// finalize fused into norm prologue (L2-hot ws/gamma/beta), nt streaming stores.
__global__ __launch_bounds__(256) void norm_kernel(
    const float* __restrict__ x, const int* __restrict__ nv,
    const float* __restrict__ gamma, const float* __restrict__ beta,
    const float* __restrict__ ws, float* __restrict__ out)
{
    __shared__ float s_sc[Fdim], s_bi[Fdim];
    __shared__ int s_nv[Bdim];
    const int tid = threadIdx.x;
    if (tid < Bdim) s_nv[tid] = nv[tid];
    __syncthreads();
    {
        int cnt = 0;
        #pragma unroll
        for (int i = 0; i < Bdim; i++) cnt += s_nv[i];
        const float inv_count = 1.0f / fmaxf((float)cnt, 1.0f);
        const float mean = ws[tid] * inv_count;
        float var = fmaf(ws[Fdim + tid], inv_count, -mean * mean);
        var = fmaxf(var, 0.0f);
        const float s = rsqrtf(var + EPS) * gamma[tid];
        s_sc[tid] = s;
        s_bi[tid] = fmaf(-mean, s, beta[tid]);
    }
    __syncthreads();

    // c = idx & 63 is loop-invariant (stride % 64 == 0): scale/bias in registers
    const int c = tid & 63;
    const fx4 sc = ((const fx4*)s_sc)[c];
    const fx4 bi = ((const fx4*)s_bi)[c];

    const int base = blockIdx.x * 256 + tid;
    const int stride = NORM_BLOCKS * 256;                      // 524288
    #pragma unroll
    for (int it = 0; it < NORM_ITERS; it++) {                  // 16 iters
        const int idx = base + it * stride;
        const int row = idx >> 6;          // 64 chunks per row; wave = one row
        const int b = row >> 13;
        const int n = row & (Ndim - 1);
        fx4* po = (fx4*)out + idx;
        if (n < s_nv[b]) {                 // wave-uniform branch
            const fx4 v = ((const fx4*)x)[idx];
            fx4 o;
            o.x = fmaf(v.x, sc.x, bi.x);
            o.y = fmaf(v.y, sc.y, bi.y);
            o.z = fmaf(v.z, sc.z, bi.z);
            o.w = fmaf(v.w, sc.w, bi.w);
            __builtin_nontemporal_store(o, po);   // write-only output stream
        } else {
            const fx4 z = {0.f, 0.f, 0.f, 0.f};
            __builtin_nontemporal_store(z, po);
        }
    }
}

extern "C" void kernel_launch(void* const* d_in, const int* in_sizes, int n_in,
                              void* d_out, int out_size, void* d_ws, size_t ws_size,
                              hipStream_t stream) {
    const float* x     = (const float*)d_in[0];   // f32 [16,8192,256]
    const int*   nv    = (const int*)d_in[1];     // int32 [16]
    const float* gamma = (const float*)d_in[2];   // f32 [256]
    const float* beta  = (const float*)d_in[3];   // f32 [256]
    float* out = (float*)d_out;
    float* ws  = (float*)d_ws;

    init_kernel<<<1, 512, 0, stream>>>(ws);
    reduce_kernel<<<RED_BLOCKS, 256, 0, stream>>>(x, nv, ws);
    norm_kernel<<<NORM_BLOCKS, 256, 0, stream>>>(x, nv, gamma, beta, ws, out);
}